// Round 5
// baseline (510.520 us; speedup 1.0000x reference)
//
#include <hip/hip_runtime.h>

#define DD     256
#define NROWS  51200   // C*S
#define NPROTO 2000
#define NP2    2016    // padded to 63 tiles of 32
#define NT     63
#define NCLSS  100

typedef _Float16 h8 __attribute__((ext_vector_type(8)));
typedef float f32x16 __attribute__((ext_vector_type(16)));

// async global->LDS, 16B per lane, linear dest (wave-uniform base + lane*16)
__device__ __forceinline__ void gll16(const void* g, void* l) {
    __builtin_amdgcn_global_load_lds(
        (const __attribute__((address_space(1))) unsigned int*)g,
        (__attribute__((address_space(3))) unsigned int*)l, 16, 0, 0);
}

// ---------------------------------------------------------------------------
// p2[p] = |proto_p|^2 ; padded entries get +1e30 so logit -> -1e30
// ---------------------------------------------------------------------------
__global__ void p2_kernel(const float* __restrict__ protos, float* __restrict__ p2) {
    int p = blockIdx.x * 256 + threadIdx.x;
    if (p >= NP2) return;
    if (p >= NPROTO) { p2[p] = 1e30f; return; }
    const float4* row = reinterpret_cast<const float4*>(protos + (size_t)p * DD);
    float s = 0.f;
    #pragma unroll 8
    for (int k = 0; k < DD / 4; ++k) {
        float4 v = row[k];
        s = fmaf(v.x, v.x, s); s = fmaf(v.y, v.y, s);
        s = fmaf(v.z, v.z, s); s = fmaf(v.w, v.w, s);
    }
    p2[p] = s;
}

// ---------------------------------------------------------------------------
// Proto images (f16 hi only):
//  PHsw: per tile [32 p][32 units of 8 f16], unit u stored at u^(p&7)
//  PTsw: per tile [256 d][36 f16] (cols 0..31 = protos; 32..35 pad, unread)
// ---------------------------------------------------------------------------
__global__ __launch_bounds__(256) void prep_proto(
    const float* __restrict__ protos,
    _Float16* __restrict__ PHsw, _Float16* __restrict__ PTsw)
{
    const int id = blockIdx.x * 256 + threadIdx.x;   // 0..64511
    const int pg = id >> 5;                          // proto 0..2015
    const int u  = id & 31;
    const int tile = pg >> 5;
    const int p = pg & 31;

    float v[8];
    #pragma unroll
    for (int j = 0; j < 8; ++j) v[j] = 0.f;
    if (pg < NPROTO) {
        const float4 a = *(const float4*)(protos + (size_t)pg * DD + u * 8);
        const float4 b = *(const float4*)(protos + (size_t)pg * DD + u * 8 + 4);
        v[0]=a.x; v[1]=a.y; v[2]=a.z; v[3]=a.w;
        v[4]=b.x; v[5]=b.y; v[6]=b.z; v[7]=b.w;
    }
    h8 ph;
    #pragma unroll
    for (int j = 0; j < 8; ++j) ph[j] = (_Float16)v[j];
    *(h8*)(PHsw + (size_t)tile * 8192 + p * 256 + (u ^ (p & 7)) * 8) = ph;
    _Float16* pt = PTsw + (size_t)tile * 9216;
    #pragma unroll
    for (int j = 0; j < 8; ++j)
        pt[(u * 8 + j) * 36 + p] = ph[j];
}

// ---------------------------------------------------------------------------
// WHsw: 8 tiles x [32 cols][32 units], B[k][c]=W[c][k], unit u at u^(c&7)
// ---------------------------------------------------------------------------
__global__ __launch_bounds__(256) void prep_w(
    const float* __restrict__ W, _Float16* __restrict__ WHsw)
{
    const int id = blockIdx.x * 256 + threadIdx.x;   // 0..8191
    const int c = id >> 5;                           // 0..255
    const int u = id & 31;
    const float4 a = *(const float4*)(W + (size_t)c * DD + u * 8);
    const float4 b = *(const float4*)(W + (size_t)c * DD + u * 8 + 4);
    h8 hv;
    hv[0]=(_Float16)a.x; hv[1]=(_Float16)a.y; hv[2]=(_Float16)a.z; hv[3]=(_Float16)a.w;
    hv[4]=(_Float16)b.x; hv[5]=(_Float16)b.y; hv[6]=(_Float16)b.z; hv[7]=(_Float16)b.w;
    *(h8*)(WHsw + (size_t)(c >> 5) * 8192 + (c & 31) * 256 + ((u ^ (c & 7)) * 8)) = hv;
}

// ---------------------------------------------------------------------------
// OWsw: 8 chunks (ct 0..3 x kh 0..1) x [32 cols][32 units]; cols 100..127 zero
// ---------------------------------------------------------------------------
__global__ __launch_bounds__(256) void prep_ow(
    const float* __restrict__ OW, _Float16* __restrict__ OWsw)
{
    const int id = blockIdx.x * 256 + threadIdx.x;   // 0..8191
    const int c = id >> 6;                           // 0..127
    const int u = id & 63;                           // 0..63
    float v[8];
    #pragma unroll
    for (int j = 0; j < 8; ++j) v[j] = 0.f;
    if (c < NCLSS) {
        const float4 a = *(const float4*)(OW + (size_t)c * 512 + u * 8);
        const float4 b = *(const float4*)(OW + (size_t)c * 512 + u * 8 + 4);
        v[0]=a.x; v[1]=a.y; v[2]=a.z; v[3]=a.w;
        v[4]=b.x; v[5]=b.y; v[6]=b.z; v[7]=b.w;
    }
    h8 hv;
    #pragma unroll
    for (int j = 0; j < 8; ++j) hv[j] = (_Float16)v[j];
    const int chunk = (c >> 5) * 2 + (u >> 5);
    const int u5 = u & 31;
    *(h8*)(OWsw + (size_t)chunk * 8192 + (c & 31) * 256 + ((u5 ^ (c & 7)) * 8)) = hv;
}

// ---------------------------------------------------------------------------
// hidden: XH = f16(relu(samples @ W^T + b)), MFMA 32x32x16, 4 waves x 32 rows
// ---------------------------------------------------------------------------
__global__ __launch_bounds__(256, 2) void hidden_kernel(
    const float* __restrict__ A, const _Float16* __restrict__ WHsw,
    const float* __restrict__ bias, _Float16* __restrict__ XH)
{
    __shared__ __align__(16) _Float16 sW[2][32 * 256];
    __shared__ float sBias[256];
    const int t = threadIdx.x;
    const int wv = t >> 6, lane = t & 63, lid = lane & 31, h = lane >> 5;
    const int rowBase = blockIdx.x * 128 + wv * 32;
    const int swz = lid & 7;

    sBias[t] = bias[t];

    h8 xa[16];
    {
        const float* arow = A + (size_t)(rowBase + lid) * DD + 8 * h;
        #pragma unroll
        for (int kc = 0; kc < 16; ++kc) {
            float4 va = *(const float4*)(arow + kc * 16);
            float4 vb = *(const float4*)(arow + kc * 16 + 4);
            h8 x;
            x[0]=(_Float16)va.x; x[1]=(_Float16)va.y; x[2]=(_Float16)va.z; x[3]=(_Float16)va.w;
            x[4]=(_Float16)vb.x; x[5]=(_Float16)vb.y; x[6]=(_Float16)vb.z; x[7]=(_Float16)vb.w;
            xa[kc] = x;
        }
    }
    #pragma unroll
    for (int i = 0; i < 4; ++i)
        gll16(WHsw + (i * 256 + t) * 8, &sW[0][(i * 256 + t) * 8]);
    __syncthreads();

    #pragma unroll
    for (int ct = 0; ct < 8; ++ct) {
        const int buf = ct & 1;
        if (ct + 1 < 8) {
            const _Float16* g = WHsw + (size_t)(ct + 1) * 8192;
            #pragma unroll
            for (int i = 0; i < 4; ++i)
                gll16(g + (i * 256 + t) * 8, &sW[buf ^ 1][(i * 256 + t) * 8]);
        }
        f32x16 c0, c1;
        #pragma unroll
        for (int r = 0; r < 16; ++r) { c0[r] = 0.f; c1[r] = 0.f; }
        const _Float16* wrow = &sW[buf][lid * 256];
        #pragma unroll
        for (int kc = 0; kc < 16; kc += 2) {
            h8 b0 = *(const h8*)(wrow + (((kc    ) * 2 + h) ^ swz) * 8);
            h8 b1 = *(const h8*)(wrow + (((kc + 1) * 2 + h) ^ swz) * 8);
            c0 = __builtin_amdgcn_mfma_f32_32x32x16_f16(xa[kc],     b0, c0, 0, 0, 0);
            c1 = __builtin_amdgcn_mfma_f32_32x32x16_f16(xa[kc + 1], b1, c1, 0, 0, 0);
        }
        const float bv = sBias[ct * 32 + lid];
        #pragma unroll
        for (int r = 0; r < 16; ++r) {
            const int n = rowBase + (r & 3) + 8 * (r >> 2) + 4 * h;
            float v = c0[r] + c1[r] + bv;
            XH[(size_t)n * DD + ct * 32 + lid] = (_Float16)fmaxf(v, 0.f);
        }
        __syncthreads();
    }
}

// ---------------------------------------------------------------------------
// MFMA flash attention. 4 waves x 32 rows = 128 rows/block, tile = 32 protos.
// Double-buffered PH+PT staged via global_load_lds; raw s_barrier + counted
// s_waitcnt vmcnt(9) so next-tile loads stay in flight ACROSS barriers
// (9 = 4 PH + 4 PT + 1 lane-masked PT per thread per tile).
// LDS: PH 2x16K + PT 2x18K + sQ 10K = 78K -> 2 blocks/CU (2 waves/SIMD).
// C layout: col=lane&31, row=(reg&3)+8*(reg>>2)+4*(lane>>5); A/B: k=8*(lane>>5)+i
// ---------------------------------------------------------------------------
__global__ __launch_bounds__(256, 2) void attn_kernel(
    const _Float16* __restrict__ XH, const _Float16* __restrict__ PHsw,
    const _Float16* __restrict__ PTsw, const float* __restrict__ P2,
    _Float16* __restrict__ XT)
{
    __shared__ __align__(16) _Float16 sPH[2][32 * 256];   // 32 KiB
    __shared__ __align__(16) _Float16 sPT[2][256 * 36];   // 36 KiB
    __shared__ __align__(16) _Float16 sQ[4][32 * 40];     // 10 KiB

    const int t = threadIdx.x;
    const int wv = t >> 6, lane = t & 63, lid = lane & 31, h = lane >> 5;
    const int rowBase = blockIdx.x * 128 + wv * 32;
    const int swz = lid & 7;

    h8 xa[16];
    {
        const _Float16* xrow = XH + (size_t)(rowBase + lid) * DD + 8 * h;
        #pragma unroll
        for (int kc = 0; kc < 16; ++kc)
            xa[kc] = *(const h8*)(xrow + kc * 16);
    }

    f32x16 acc[8], accL;
    #pragma unroll
    for (int f = 0; f < 8; ++f)
        #pragma unroll
        for (int r = 0; r < 16; ++r) acc[f][r] = 0.f;
    #pragma unroll
    for (int r = 0; r < 16; ++r) accL[r] = 0.f;

    float m[16];
    #pragma unroll
    for (int r = 0; r < 16; ++r) m[r] = -3e38f;

    h8 ones;
    #pragma unroll
    for (int j = 0; j < 8; ++j) ones[j] = (_Float16)1.f;

    // stage macro: 9 vmcnt-ops per thread, wave-uniform (4 PH, 4 PT, 1 masked PT)
    #define STAGE(tl, bf)                                                        \
    {                                                                            \
        const _Float16* g0 = PHsw + (size_t)(tl) * 8192;                         \
        const _Float16* g2 = PTsw + (size_t)(tl) * 9216;                         \
        _Pragma("unroll")                                                        \
        for (int i = 0; i < 4; ++i)                                              \
            gll16(g0 + (i * 256 + t) * 8, &sPH[bf][(i * 256 + t) * 8]);          \
        _Pragma("unroll")                                                        \
        for (int i = 0; i < 4; ++i)                                              \
            gll16(g2 + (i * 256 + t) * 8, &sPT[bf][(i * 256 + t) * 8]);          \
        if (lane < 32)                                                           \
            gll16(g2 + (1024 + wv * 32 + lane) * 8,                              \
                  &sPT[bf][(1024 + wv * 32 + lane) * 8]);                        \
    }

    STAGE(0, 0);   // prologue: tile 0 in flight

    for (int tile = 0; tile < NT; ++tile) {
        const int buf = tile & 1;
        if (tile + 1 < NT) {
            STAGE(tile + 1, buf ^ 1);
            asm volatile("s_waitcnt vmcnt(9)" ::: "memory");  // tile data landed
        } else {
            asm volatile("s_waitcnt vmcnt(0)" ::: "memory");
        }
        __builtin_amdgcn_s_barrier();    // all waves' tile data ready

        const float p2v = P2[tile * 32 + lid];   // L2-hit, covered by QK

        // ---- QK (hi only), 2 independent chains ----
        f32x16 S0, S1;
        #pragma unroll
        for (int r = 0; r < 16; ++r) { S0[r] = 0.f; S1[r] = 0.f; }
        {
            const _Float16* phrow = &sPH[buf][lid * 256];
            __builtin_amdgcn_s_setprio(1);
            #pragma unroll
            for (int kc = 0; kc < 16; kc += 2) {
                h8 b0 = *(const h8*)(phrow + (((kc    ) * 2 + h) ^ swz) * 8);
                h8 b1 = *(const h8*)(phrow + (((kc + 1) * 2 + h) ^ swz) * 8);
                S0 = __builtin_amdgcn_mfma_f32_32x32x16_f16(xa[kc],     b0, S0, 0, 0, 0);
                S1 = __builtin_amdgcn_mfma_f32_32x32x16_f16(xa[kc + 1], b1, S1, 0, 0, 0);
            }
            __builtin_amdgcn_s_setprio(0);
        }
        float S[16];
        #pragma unroll
        for (int r = 0; r < 16; ++r) S[r] = 2.f * (S0[r] + S1[r]) - p2v;

        // ---- defer-max online softmax (THR=8, f16-safe) ----
        float ex = S[0] - m[0];
        #pragma unroll
        for (int r = 1; r < 16; ++r) ex = fmaxf(ex, S[r] - m[r]);
        if (__any(ex > 8.f)) {
            float w[16];
            #pragma unroll
            for (int r = 0; r < 16; ++r) w[r] = S[r];
            #pragma unroll
            for (int msk = 1; msk < 32; msk <<= 1)
                #pragma unroll
                for (int r = 0; r < 16; ++r)
                    w[r] = fmaxf(w[r], __shfl_xor(w[r], msk, 64));
            #pragma unroll
            for (int r = 0; r < 16; ++r) {
                float mn = fmaxf(m[r], w[r]);
                float sc = __expf(m[r] - mn);
                m[r] = mn;
                #pragma unroll
                for (int f = 0; f < 8; ++f) acc[f][r] *= sc;
                accL[r] *= sc;
            }
        }
        float w[16];
        #pragma unroll
        for (int r = 0; r < 16; ++r) w[r] = __expf(S[r] - m[r]);

        // ---- q tile to LDS (wave-local transpose) ----
        {
            _Float16* q = sQ[wv];
            #pragma unroll
            for (int r = 0; r < 16; ++r) {
                const int n = (r & 3) + 8 * (r >> 2) + 4 * h;
                q[n * 40 + lid] = (_Float16)w[r];
            }
        }

        // ---- PV + ones-column denominator ----
        {
            const _Float16* q = sQ[wv] + lid * 40 + 8 * h;
            h8 qa0 = *(const h8*)(q);
            h8 qa1 = *(const h8*)(q + 16);
            __builtin_amdgcn_s_setprio(1);
            #pragma unroll
            for (int f = 0; f < 8; ++f) {
                const _Float16* pt = &sPT[buf][(f * 32 + lid) * 36 + 8 * h];
                h8 b0 = *(const h8*)(pt);
                h8 b1 = *(const h8*)(pt + 16);
                acc[f] = __builtin_amdgcn_mfma_f32_32x32x16_f16(qa0, b0, acc[f], 0, 0, 0);
                acc[f] = __builtin_amdgcn_mfma_f32_32x32x16_f16(qa1, b1, acc[f], 0, 0, 0);
            }
            accL = __builtin_amdgcn_mfma_f32_32x32x16_f16(qa0, ones, accL, 0, 0, 0);
            accL = __builtin_amdgcn_mfma_f32_32x32x16_f16(qa1, ones, accL, 0, 0, 0);
            __builtin_amdgcn_s_setprio(0);
        }
        asm volatile("s_waitcnt lgkmcnt(0)" ::: "memory");  // reads retired
        __builtin_amdgcn_s_barrier();    // gate buffer overwrite next iter
    }
    #undef STAGE

    // ---- epilogue: x_tilde = acc / l ----
    #pragma unroll
    for (int r = 0; r < 16; ++r) {
        const float inv = 1.f / accL[r];
        const int n = rowBase + (r & 3) + 8 * (r >> 2) + 4 * h;
        #pragma unroll
        for (int f = 0; f < 8; ++f)
            XT[(size_t)n * DD + f * 32 + lid] = (_Float16)(acc[f][r] * inv);
    }
}

// ---------------------------------------------------------------------------
// out: OUT[n][c] = [x | x_tilde] @ OW^T, MFMA, K=512, cols padded to 128
// ---------------------------------------------------------------------------
__global__ __launch_bounds__(256, 2) void out_kernel(
    const _Float16* __restrict__ XH, const _Float16* __restrict__ XT,
    const _Float16* __restrict__ OWsw, float* __restrict__ OUT)
{
    __shared__ __align__(16) _Float16 sW[2][32 * 256];
    const int t = threadIdx.x;
    const int wv = t >> 6, lane = t & 63, lid = lane & 31, h = lane >> 5;
    const int rowBase = blockIdx.x * 128 + wv * 32;
    const int swz = lid & 7;

    h8 xa[32];
    {
        const _Float16* x0 = XH + (size_t)(rowBase + lid) * DD + 8 * h;
        const _Float16* x1 = XT + (size_t)(rowBase + lid) * DD + 8 * h;
        #pragma unroll
        for (int kc = 0; kc < 16; ++kc) xa[kc]      = *(const h8*)(x0 + kc * 16);
        #pragma unroll
        for (int kc = 0; kc < 16; ++kc) xa[16 + kc] = *(const h8*)(x1 + kc * 16);
    }

    f32x16 acc[4];
    #pragma unroll
    for (int q = 0; q < 4; ++q)
        #pragma unroll
        for (int r = 0; r < 16; ++r) acc[q][r] = 0.f;

    #pragma unroll
    for (int i = 0; i < 4; ++i)
        gll16(OWsw + (i * 256 + t) * 8, &sW[0][(i * 256 + t) * 8]);
    __syncthreads();

    #pragma unroll
    for (int ch = 0; ch < 8; ++ch) {
        const int buf = ch & 1;
        if (ch + 1 < 8) {
            const _Float16* g = OWsw + (size_t)(ch + 1) * 8192;
            #pragma unroll
            for (int i = 0; i < 4; ++i)
                gll16(g + (i * 256 + t) * 8, &sW[buf ^ 1][(i * 256 + t) * 8]);
        }
        const int ct = ch >> 1, kh = ch & 1;
        const _Float16* wrow = &sW[buf][lid * 256];
        f32x16 a = acc[ct];
        #pragma unroll
        for (int kc = 0; kc < 16; ++kc) {
            h8 b = *(const h8*)(wrow + ((kc * 2 + h) ^ swz) * 8);
            a = __builtin_amdgcn_mfma_f32_32x32x16_f16(xa[kh * 16 + kc], b, a, 0, 0, 0);
        }
        acc[ct] = a;
        __syncthreads();
    }

    #pragma unroll
    for (int ct = 0; ct < 4; ++ct) {
        const int col = ct * 32 + lid;
        if (col < NCLSS) {
            #pragma unroll
            for (int r = 0; r < 16; ++r) {
                const int n = rowBase + (r & 3) + 8 * (r >> 2) + 4 * h;
                OUT[(size_t)n * NCLSS + col] = acc[ct][r];
            }
        }
    }
}

// ---------------------------------------------------------------------------
extern "C" void kernel_launch(void* const* d_in, const int* in_sizes, int n_in,
                              void* d_out, int out_size, void* d_ws, size_t ws_size,
                              hipStream_t stream) {
    const float* samples  = (const float*)d_in[0];
    const float* hidden_w = (const float*)d_in[1];
    const float* hidden_b = (const float*)d_in[2];
    const float* protos   = (const float*)d_in[3];
    const float* output_w = (const float*)d_in[4];
    float* out = (float*)d_out;

    char* ws = (char*)d_ws;
    _Float16* XH   = (_Float16*)(ws);                  // 26,214,400
    _Float16* XT   = (_Float16*)(ws + 26214400);       // 26,214,400
    _Float16* PHsw = (_Float16*)(ws + 52428800);       // 63*8192*2 = 1,032,192
    _Float16* PTsw = (_Float16*)(ws + 53460992);       // 63*9216*2 = 1,161,216
    _Float16* WHsw = (_Float16*)(ws + 54622208);       // 131,072
    _Float16* OWsw = (_Float16*)(ws + 54753280);       // 131,072
    float*    P2   = (float*)   (ws + 54884352);       // 8,064

    p2_kernel <<<8,   256, 0, stream>>>(protos, P2);
    prep_proto<<<252, 256, 0, stream>>>(protos, PHsw, PTsw);
    prep_w    <<<32,  256, 0, stream>>>(hidden_w, WHsw);
    prep_ow   <<<32,  256, 0, stream>>>(output_w, OWsw);
    hidden_kernel<<<400, 256, 0, stream>>>(samples, WHsw, hidden_b, XH);
    attn_kernel  <<<400, 256, 0, stream>>>(XH, PHsw, PTsw, P2, XT);
    out_kernel   <<<400, 256, 0, stream>>>(XH, XT, OWsw, out);
}